// Round 13
// baseline (192.773 us; speedup 1.0000x reference)
//
#include <hip/hip_runtime.h>

typedef unsigned short u16;
typedef __attribute__((ext_vector_type(8))) short bf16x8;
typedef __attribute__((ext_vector_type(4))) float f32x4;

constexpr int B_ = 4096, IN_ = 512, T_ = 10, E_ = 16, S_ = 2, K_ = 4, W_ = 1024, HD_ = 64;
constexpr int XROW = IN_ + T_;             // 522
constexpr int NPAIR = B_ * (K_ + S_);      // 24576
constexpr int MTU = 208;                   // worst-case sum of ceil(cnt/128) over 18 groups
constexpr int GEMM_GRID = MTU * 8;         // 1664
constexpr int GB_ = 16;                    // gate blocks
constexpr int CB_GRID = 1034;              // worst-case combine blocks (sum ceil(tcnt/4))

// meta (ints): 0 counts_e[16] | 16 bases_e[16] | 48 tprefix128[19]
//            | 70 pb[10] | 80 bp[11] | 91 tcnt[10]

#define GLL16(g, l) __builtin_amdgcn_global_load_lds( \
    (const __attribute__((address_space(1))) void*)(g), \
    (__attribute__((address_space(3))) void*)(l), 16, 0, 0)

__device__ __forceinline__ u16 f2bf(float x) {
    unsigned u = __float_as_uint(x);
    return (u16)((u + 0x7fffu + ((u >> 16) & 1u)) >> 16);
}
__device__ __forceinline__ float bf2f(u16 b) { return __uint_as_float(((unsigned)b) << 16); }

// ---------------- feat fp32 -> bf16 ----------------
__global__ __launch_bounds__(256) void featconv(const float* __restrict__ x, u16* __restrict__ featb) {
    int i = blockIdx.x * 256 + threadIdx.x;
    int b = i >> 8;
    int c2 = (i & 255) * 2;
    float2 v = *(const float2*)(x + (size_t)b * XROW + c2);
    ushort2 o;
    o.x = f2bf(v.x);
    o.y = f2bf(v.y);
    *(ushort2*)(featb + (size_t)b * IN_ + c2) = o;
}

// ---------------- gating: LDS histograms, zero global atomics ----------------
__global__ __launch_bounds__(256) void gate_kernel(const float* __restrict__ x, const float* __restrict__ gk,
                                                   int* __restrict__ top4p, float* __restrict__ w6,
                                                   int* __restrict__ task_id, int* __restrict__ tpp,
                                                   int* __restrict__ bct_e, int* __restrict__ bct_t) {
    __shared__ float sgk[T_ * E_];
    __shared__ int hist[E_];
    __shared__ int thist[T_];
    int blk = blockIdx.x, tid = threadIdx.x;
    int b = blk * 256 + tid;
    if (tid < T_ * E_) sgk[tid] = gk[tid];
    if (tid < E_) hist[tid] = 0;
    if (tid < T_) thist[tid] = 0;
    __syncthreads();
    float tv[T_];
#pragma unroll
    for (int i = 0; i < T_; ++i) tv[i] = x[(size_t)b * XROW + IN_ + i];
    float lg[E_];
#pragma unroll
    for (int e = 0; e < E_; ++e) {
        float s = 0.f;
#pragma unroll
        for (int i = 0; i < T_; ++i) s += tv[i] * sgk[i * E_ + e];
        lg[e] = s;
    }
    int idx[K_]; float val[K_];
#pragma unroll
    for (int k = 0; k < K_; ++k) {
        int bi = 0; float bv = -1e30f;
#pragma unroll
        for (int e = 0; e < E_; ++e)
            if (lg[e] > bv) { bv = lg[e]; bi = e; }
        idx[k] = bi; val[k] = bv; lg[bi] = -1e30f;
    }
    float m = val[0];
    float ex[K_]; float s = 0.f;
#pragma unroll
    for (int k = 0; k < K_; ++k) { ex[k] = expf(val[k] - m); s += ex[k]; }
    float inv = 1.f / s;
#pragma unroll
    for (int k = 0; k < K_; ++k) {
        int lp = atomicAdd(&hist[idx[k]], 1);
        top4p[b * K_ + k] = idx[k] | (lp << 8);
        w6[b * 6 + k] = ex[k] * inv;
    }
    w6[b * 6 + 4] = 0.5f;
    w6[b * 6 + 5] = 0.5f;
    int ti = 0; float tb = tv[0];
#pragma unroll
    for (int i = 1; i < T_; ++i)
        if (tv[i] > tb) { tb = tv[i]; ti = i; }
    task_id[b] = ti;
    tpp[b] = atomicAdd(&thist[ti], 1);
    __syncthreads();
    if (tid < E_) bct_e[blk * E_ + tid] = hist[tid];
    if (tid < T_) bct_t[blk * T_ + tid] = thist[tid];
}

// ---------------- table build (one block of 64; parallel global sums, serial LDS prefixes) ----------------
__global__ void build_tables(const int* __restrict__ bct_e, const int* __restrict__ bct_t,
                             int* __restrict__ meta, int* __restrict__ blockbase,
                             int* __restrict__ tblockbase) {
    __shared__ int cnt_s[E_], tcnt_s[T_], base_s[E_], pb_s[T_];
    int tid = threadIdx.x;
    if (tid < E_) {
        int s = 0;
        for (int blk = 0; blk < GB_; ++blk) s += bct_e[blk * E_ + tid];
        cnt_s[tid] = s;
        meta[tid] = s;
    }
    if (tid >= 32 && tid < 32 + T_) {
        int t = tid - 32;
        int s = 0;
        for (int blk = 0; blk < GB_; ++blk) s += bct_t[blk * T_ + t];
        tcnt_s[t] = s;
        meta[91 + t] = s;
    }
    __syncthreads();
    if (tid == 0) {
        int a = 0;
        for (int e = 0; e < E_; ++e) { base_s[e] = a; meta[16 + e] = a; a += cnt_s[e]; }
        int t = 0;
        for (int g = 0; g < 18; ++g) { meta[48 + g] = t; int c = (g < 16) ? cnt_s[g] : B_; t += (c + 127) >> 7; }
        meta[66] = t;
        int pr = 0, br = 0;
        for (int i = 0; i < T_; ++i) {
            pb_s[i] = pr;
            meta[70 + i] = pr;
            meta[80 + i] = br;
            pr += ((tcnt_s[i] + 3) >> 2) << 2;
            br += (tcnt_s[i] + 3) >> 2;
        }
        meta[90] = br;
    }
    __syncthreads();
    if (tid < E_) {
        int run = base_s[tid];
        for (int blk = 0; blk < GB_; ++blk) { blockbase[blk * E_ + tid] = run; run += bct_e[blk * E_ + tid]; }
    }
    if (tid >= 32 && tid < 32 + T_) {
        int t = tid - 32;
        int run = pb_s[t];
        for (int blk = 0; blk < GB_; ++blk) { tblockbase[blk * T_ + t] = run; run += bct_t[blk * T_ + t]; }
    }
}

// ---------------- scatter: pure writes ----------------
__global__ __launch_bounds__(256) void scatter_kernel(const int* __restrict__ top4p,
                                                      const int* __restrict__ blockbase,
                                                      const int* __restrict__ task_id, const int* __restrict__ tpp,
                                                      const int* __restrict__ tblockbase,
                                                      int* __restrict__ pair_sample, int* __restrict__ pair_dst,
                                                      int* __restrict__ torder) {
    int blk = blockIdx.x, tid = threadIdx.x;
    int b = blk * 256 + tid;
#pragma unroll
    for (int k = 0; k < K_; ++k) {
        int v = top4p[b * K_ + k];
        int e = v & 0xFF, lp = v >> 8;
        int p = blockbase[blk * E_ + e] + lp;
        pair_sample[p] = b;
        pair_dst[p] = b * 6 + k;
    }
    pair_sample[B_ * K_ + b] = b;       pair_dst[B_ * K_ + b] = b * 6 + 4;
    pair_sample[B_ * K_ + B_ + b] = b;  pair_dst[B_ * K_ + B_ + b] = b * 6 + 5;
    torder[tblockbase[blk * T_ + task_id[b]] + tpp[b]] = b;
}

// ---------------- plain fp32 -> bf16 convert (hk) ----------------
__global__ __launch_bounds__(256) void convbf16(const float* __restrict__ in, u16* __restrict__ out) {
    int i = blockIdx.x * 256 + threadIdx.x;
    float4 v = ((const float4*)in)[i];
    ushort4 o;
    o.x = f2bf(v.x); o.y = f2bf(v.y); o.z = f2bf(v.z); o.w = f2bf(v.w);
    ((ushort4*)out)[i] = o;
}

// ------------- transpose-convert: fp32 [K][N] -> bf16 [N][K], 64k x 32n tiles, 16B stores -------------
__global__ __launch_bounds__(256) void transconv3(const float* __restrict__ srcA, const float* __restrict__ srcB,
                                                  int splitZ, u16* __restrict__ out, int K, int N) {
    __shared__ float tile[64][33];
    int z = blockIdx.z;
    const float* src = (z < splitZ) ? (srcA + (size_t)z * K * N) : (srcB + (size_t)(z - splitZ) * K * N);
    int k0 = blockIdx.y * 64, n0 = blockIdx.x * 32;
    int tid = threadIdx.x;
    int r = tid >> 2, c8 = (tid & 3) * 8;
    const float* s0 = src + (size_t)(k0 + r) * N + n0 + c8;
    float4 v0 = *(const float4*)s0;
    float4 v1 = *(const float4*)(s0 + 4);
    tile[r][c8 + 0] = v0.x; tile[r][c8 + 1] = v0.y; tile[r][c8 + 2] = v0.z; tile[r][c8 + 3] = v0.w;
    tile[r][c8 + 4] = v1.x; tile[r][c8 + 5] = v1.y; tile[r][c8 + 6] = v1.z; tile[r][c8 + 7] = v1.w;
    __syncthreads();
    int n = tid >> 3, kc = (tid & 7) * 8;
    u16 o[8];
#pragma unroll
    for (int j = 0; j < 8; ++j) o[j] = f2bf(tile[kc + j][n]);
    *(bf16x8*)(out + (size_t)z * N * K + (size_t)(n0 + n) * K + k0 + kc) = *(const bf16x8*)o;
}

// ------------- grouped GEMM, BM=128 BN=128 BK=32, 3-buffer rotation + counted vmcnt(4) -------------
// Race-proofing (R10/R11/R12 lessons): raw s_barrier alone orders memory ops but NOT register-only
// MFMAs (rule #18) — compiler could sink {lgkmcnt + MFMA} past the barrier, so a wave could pass
// the rendezvous with ds_reads still outstanding while another wave's global_load_lds overwrites
// the buffer. Fix kit: sched_barrier(0) pins ALL instructions at the loop boundary; bottom wait
// includes lgkmcnt(0) (free — reads already consumed) so ds_reads drain before the barrier.
template <int K, int LAYER>
__global__ __launch_bounds__(256, 3) void gemm8(const u16* __restrict__ Asrc, const u16* __restrict__ wT,
                                                const float* __restrict__ rbias, const float* __restrict__ sbias,
                                                const int* __restrict__ pair_sample, const int* __restrict__ pair_dst,
                                                const int* __restrict__ meta, u16* __restrict__ outp) {
    __shared__ char lds[49152];   // 3 bufs x 16KB: A [128][64B] @0, B [128][64B] @8192 ; C restage reuses 0..32KB
    const int* tpre = meta + 48;
    const int nwg = tpre[18] * 8;                      // active blocks (runtime)
    int p = blockIdx.x;
    if (p >= nwg) return;
    // runtime-balanced bijective XCD swizzle; mtu-major within each XCD's chunk
    int q = nwg >> 3, r8 = nwg & 7;
    int xcd = p & 7, iofs = p >> 3;
    int lid = (xcd < r8 ? xcd * (q + 1) : r8 * (q + 1) + (xcd - r8) * q) + iofs;
    int mtu = lid >> 3, nt = lid & 7;
    int e = 0;
    while (mtu >= tpre[e + 1]) ++e;
    int mt = mtu - tpre[e];
    int off, cnt;
    if (e < E_) { off = meta[16 + e]; cnt = meta[e]; }
    else        { off = B_ * K_ + (e - E_) * B_; cnt = B_; }

    const int tid = threadIdx.x;
    // staging role: row = r2*64 + (tid>>2), 16B chunk slot = tid&3; source chunk = slot ^ ((row>>1)&3)
    const int srow = tid >> 2, sslot = tid & 3;
    const u16* wTe = wT + (size_t)e * W_ * K;
    const u16* ab[2];
    const u16* bb[2];
#pragma unroll
    for (int r = 0; r < 2; ++r) {
        int row = r * 64 + srow;
        int gchunk = sslot ^ ((row >> 1) & 3);
        int gm = mt * 128 + row;
        if (gm >= cnt) gm = cnt - 1;
        int arow = (LAYER == 1) ? pair_sample[off + gm] : (off + gm);
        ab[r] = Asrc + (size_t)arow * K + gchunk * 8;
        bb[r] = wTe + (size_t)(nt * 128 + row) * K + gchunk * 8;
    }

    // 4 loads per stage per thread
    auto STAGE = [&](int kt, int buf) {
        char* base = lds + buf * 16384;
        GLL16(ab[0] + kt * 32, base + tid * 16);
        GLL16(ab[1] + kt * 32, base + 4096 + tid * 16);
        GLL16(bb[0] + kt * 32, base + 8192 + tid * 16);
        GLL16(bb[1] + kt * 32, base + 12288 + tid * 16);
    };

    f32x4 acc[4][4];
#pragma unroll
    for (int i = 0; i < 4; ++i)
#pragma unroll
        for (int j = 0; j < 4; ++j) acc[i][j] = (f32x4){0.f, 0.f, 0.f, 0.f};

    const int lane = tid & 63, wid = tid >> 6;
    const int wr = wid >> 1, wc = wid & 1;             // wave tile 64x64
    const int fr = lane & 15;
    const int fkb = (lane >> 4) * 16;                  // byte offset of the lane's 8-elem k-chunk (k=0..31)

    constexpr int NKT = K / 32;
    STAGE(0, 0);
    __builtin_amdgcn_sched_barrier(0);                 // pin issue order: tile0's loads are the oldest
    STAGE(1, 1);
    asm volatile("s_waitcnt vmcnt(4)" ::: "memory");   // tile 0 landed; tile 1 still flying
    __builtin_amdgcn_s_barrier();
    asm volatile("" ::: "memory");
    __builtin_amdgcn_sched_barrier(0);
    int rb = 0, sb = 2;
    for (int kt = 0; kt < NKT; ++kt) {
        if (kt + 2 < NKT) {
            STAGE(kt + 2, sb);
            sb = (sb == 2) ? 0 : sb + 1;
        }
        char* A = lds + rb * 16384;
        char* Bv = A + 8192;
        bf16x8 af[4], bf[4];
#pragma unroll
        for (int i = 0; i < 4; ++i) {
            int arow = wr * 64 + i * 16 + fr;
            af[i] = *(const bf16x8*)(A + arow * 64 + (fkb ^ (((arow >> 1) & 3) << 4)));
            int brow = wc * 64 + i * 16 + fr;
            bf[i] = *(const bf16x8*)(Bv + brow * 64 + (fkb ^ (((brow >> 1) & 3) << 4)));
        }
#pragma unroll
        for (int i = 0; i < 4; ++i)
#pragma unroll
            for (int j = 0; j < 4; ++j)
                acc[i][j] = __builtin_amdgcn_mfma_f32_16x16x32_bf16(af[i], bf[j], acc[i][j], 0, 0, 0);
        __builtin_amdgcn_sched_barrier(0);             // NOTHING (incl. MFMA) may sink below this point
        if (kt + 2 < NKT) {
            asm volatile("s_waitcnt vmcnt(4) lgkmcnt(0)" ::: "memory");  // next tile landed; kt+2 in flight
        } else {
            asm volatile("s_waitcnt vmcnt(0) lgkmcnt(0)" ::: "memory");  // tail: drain
        }
        __builtin_amdgcn_s_barrier();
        asm volatile("" ::: "memory");
        __builtin_amdgcn_sched_barrier(0);             // NOTHING may hoist above the barrier
        rb = (rb == 2) ? 0 : rb + 1;
    }

    // ---- epilogue: bias+relu -> bf16 C-tile in LDS (128 rows x 256B, XOR slots), coalesced stores ----
    const float* bias = (e < E_) ? (rbias + (size_t)e * W_) : (sbias + (size_t)(e - E_) * W_);
#pragma unroll
    for (int i = 0; i < 4; ++i) {
#pragma unroll
        for (int reg = 0; reg < 4; ++reg) {
            int r = wr * 64 + i * 16 + (lane >> 4) * 4 + reg;
#pragma unroll
            for (int j = 0; j < 4; ++j) {
                int c = wc * 64 + j * 16 + fr;
                float v = acc[i][j][reg] + bias[nt * 128 + c];
                *(u16*)(lds + r * 256 + ((c * 2) ^ ((r & 7) << 4))) = f2bf(fmaxf(v, 0.f));
            }
        }
    }
    __syncthreads();
#pragma unroll
    for (int rr = 0; rr < 8; ++rr) {
        int flat = rr * 4096 + tid * 16;
        int r = flat >> 8;                 // row 0..127
        int co = flat & 255;               // byte offset within row
        int m = mt * 128 + r;
        if (m < cnt) {
            int outrow = (LAYER == 1) ? (off + m) : pair_dst[off + m];
            bf16x8 v = *(const bf16x8*)(lds + r * 256 + (co ^ ((r & 7) << 4)));
            *(bf16x8*)(outp + (size_t)outrow * W_ + nt * 128 + (co >> 1)) = v;
        }
    }
}

// ------------- combine: 4 same-task samples/block; tanh(sum) then head GEMV -------------
__global__ __launch_bounds__(256) void combine4(const u16* __restrict__ h2, const float* __restrict__ w6,
                                                const int* __restrict__ torder, const int* __restrict__ meta,
                                                const u16* __restrict__ hkb, const float* __restrict__ hb,
                                                float* __restrict__ out) {
    __shared__ float f[4][W_];
    __shared__ float partials[4][4][64];
    const int* bp = meta + 80;
    int blk = blockIdx.x;
    if (blk >= bp[T_]) return;
    int t = 0;
    while (blk >= bp[t + 1]) ++t;
    int slot0 = meta[70 + t] + (blk - bp[t]) * 4;
    int vend  = meta[70 + t] + meta[91 + t];
    int tid = threadIdx.x;
    int s0 = torder[slot0];
    int smp[4];
#pragma unroll
    for (int i = 0; i < 4; ++i) {
        int v = torder[slot0 + i];
        smp[i] = (slot0 + i < vend) ? v : s0;
    }
#pragma unroll
    for (int s = 0; s < 4; ++s) {
        int b = smp[s];
        float wsl[6];
#pragma unroll
        for (int qq = 0; qq < 6; ++qq) wsl[qq] = w6[b * 6 + qq];
        float sum[4] = {0.f, 0.f, 0.f, 0.f};
#pragma unroll
        for (int qq = 0; qq < 6; ++qq) {
            ushort4 v = *(const ushort4*)(h2 + (size_t)(b * 6 + qq) * W_ + tid * 4);
            sum[0] += wsl[qq] * bf2f(v.x);
            sum[1] += wsl[qq] * bf2f(v.y);
            sum[2] += wsl[qq] * bf2f(v.z);
            sum[3] += wsl[qq] * bf2f(v.w);
        }
        float4 tf;
        tf.x = tanhf(sum[0]); tf.y = tanhf(sum[1]); tf.z = tanhf(sum[2]); tf.w = tanhf(sum[3]);
        *(float4*)(&f[s][tid * 4]) = tf;               // single b128 store: conflict-free
    }
    __syncthreads();
    int d = tid & 63, g = tid >> 6;
    const u16* hp = hkb + (size_t)t * W_ * HD_ + d;
    float acc[4] = {0.f, 0.f, 0.f, 0.f};
#pragma unroll 4
    for (int w = g; w < W_; w += 4) {
        float hv = bf2f(hp[(size_t)w * HD_]);
#pragma unroll
        for (int s = 0; s < 4; ++s) acc[s] += f[s][w] * hv;
    }
#pragma unroll
    for (int s = 0; s < 4; ++s) partials[g][s][d] = acc[s];
    __syncthreads();
    int ss = tid >> 6, dd = tid & 63;
    float r = partials[0][ss][dd] + partials[1][ss][dd] + partials[2][ss][dd] + partials[3][ss][dd]
            + hb[t * HD_ + dd];
    out[(size_t)smp[ss] * HD_ + dd] = r;
}

extern "C" void kernel_launch(void* const* d_in, const int* in_sizes, int n_in,
                              void* d_out, int out_size, void* d_ws, size_t ws_size,
                              hipStream_t stream) {
    const float* x   = (const float*)d_in[0];
    const float* gk  = (const float*)d_in[1];
    const float* rk0 = (const float*)d_in[2];
    const float* rb0 = (const float*)d_in[3];
    const float* rk1 = (const float*)d_in[4];
    const float* rb1 = (const float*)d_in[5];
    const float* sk0 = (const float*)d_in[6];
    const float* sb0 = (const float*)d_in[7];
    const float* sk1 = (const float*)d_in[8];
    const float* sb1 = (const float*)d_in[9];
    const float* hk  = (const float*)d_in[10];
    const float* hb  = (const float*)d_in[11];
    float* out = (float*)d_out;
    (void)in_sizes; (void)n_in; (void)out_size; (void)ws_size;

    char* ws = (char*)d_ws;
    size_t o = 0;
    auto alloc = [&](size_t bytes) { char* p = ws + o; o += (bytes + 255) & ~(size_t)255; return p; };
    int* meta        = (int*)alloc(512);
    int* bct_e       = (int*)alloc((size_t)GB_ * E_ * 4);
    int* bct_t       = (int*)alloc((size_t)GB_ * T_ * 4);
    int* blockbase   = (int*)alloc((size_t)GB_ * E_ * 4);
    int* tblockbase  = (int*)alloc((size_t)GB_ * T_ * 4);
    int* top4p       = (int*)alloc((size_t)B_ * K_ * 4);
    float* w6        = (float*)alloc((size_t)B_ * 6 * 4);
    int* task_id     = (int*)alloc((size_t)B_ * 4);
    int* tpp         = (int*)alloc((size_t)B_ * 4);
    int* pair_sample = (int*)alloc((size_t)NPAIR * 4);
    int* pair_dst    = (int*)alloc((size_t)NPAIR * 4);
    int* torder      = (int*)alloc((size_t)(B_ + 64) * 4);
    u16* featb       = (u16*)alloc((size_t)B_ * IN_ * 2);
    u16* w0T         = (u16*)alloc((size_t)(E_ + S_) * W_ * IN_ * 2);
    u16* w1T         = (u16*)alloc((size_t)(E_ + S_) * W_ * W_ * 2);
    u16* hkb         = (u16*)alloc((size_t)T_ * W_ * HD_ * 2);
    u16* h1          = (u16*)alloc((size_t)NPAIR * W_ * 2);
    u16* h2          = (u16*)alloc((size_t)NPAIR * W_ * 2);

    featconv<<<B_, 256, 0, stream>>>(x, featb);
    gate_kernel<<<GB_, 256, 0, stream>>>(x, gk, top4p, w6, task_id, tpp, bct_e, bct_t);
    build_tables<<<1, 64, 0, stream>>>(bct_e, bct_t, meta, blockbase, tblockbase);
    scatter_kernel<<<GB_, 256, 0, stream>>>(top4p, blockbase, task_id, tpp, tblockbase,
                                            pair_sample, pair_dst, torder);
    transconv3<<<dim3(W_ / 32, IN_ / 64, E_ + S_), 256, 0, stream>>>(rk0, sk0, E_, w0T, IN_, W_);
    transconv3<<<dim3(W_ / 32, W_ / 64, E_ + S_), 256, 0, stream>>>(rk1, sk1, E_, w1T, W_, W_);
    convbf16<<<(T_ * W_ * HD_) / 1024, 256, 0, stream>>>(hk, hkb);
    gemm8<IN_, 1><<<GEMM_GRID, 256, 0, stream>>>(featb, w0T, rb0, sb0, pair_sample, pair_dst, meta, h1);
    gemm8<W_, 2><<<GEMM_GRID, 256, 0, stream>>>(h1, w1T, rb1, sb1, pair_sample, pair_dst, meta, h2);
    combine4<<<CB_GRID, 256, 0, stream>>>(h2, w6, torder, meta, hkb, hb, out);
}

// Round 14
// 188.093 us; speedup vs baseline: 1.0249x; 1.0249x over previous
//
#include <hip/hip_runtime.h>

typedef unsigned short u16;
typedef __attribute__((ext_vector_type(8))) short bf16x8;
typedef __attribute__((ext_vector_type(4))) float f32x4;

constexpr int B_ = 4096, IN_ = 512, T_ = 10, E_ = 16, S_ = 2, K_ = 4, W_ = 1024, HD_ = 64;
constexpr int XROW = IN_ + T_;             // 522
constexpr int NPAIR = B_ * (K_ + S_);      // 24576
constexpr int MTU = 208;                   // worst-case sum of ceil(cnt/128) over 18 groups
constexpr int GEMM_GRID = MTU * 8;         // 1664
constexpr int GB_ = 16;                    // gate blocks
constexpr int CB_GRID = 1034;              // worst-case combine blocks (sum ceil(tcnt/4))

// meta (ints): 0 counts_e[16] | 16 bases_e[16] | 48 tprefix128[19]
//            | 70 pb[10] | 80 bp[11] | 91 tcnt[10]

#define GLL16(g, l) __builtin_amdgcn_global_load_lds( \
    (const __attribute__((address_space(1))) void*)(g), \
    (__attribute__((address_space(3))) void*)(l), 16, 0, 0)

__device__ __forceinline__ u16 f2bf(float x) {
    unsigned u = __float_as_uint(x);
    return (u16)((u + 0x7fffu + ((u >> 16) & 1u)) >> 16);
}
__device__ __forceinline__ float bf2f(u16 b) { return __uint_as_float(((unsigned)b) << 16); }

// fast tanh: 1 - 2/(e^{2x}+1); v_exp + v_rcp, saturates correctly at +-1
__device__ __forceinline__ float fast_tanh(float x) {
    float t = __expf(2.f * x);
    return 1.f - 2.f * __builtin_amdgcn_rcpf(t + 1.f);
}

// ---------------- feat fp32 -> bf16 ----------------
__global__ __launch_bounds__(256) void featconv(const float* __restrict__ x, u16* __restrict__ featb) {
    int i = blockIdx.x * 256 + threadIdx.x;
    int b = i >> 8;
    int c2 = (i & 255) * 2;
    float2 v = *(const float2*)(x + (size_t)b * XROW + c2);
    ushort2 o;
    o.x = f2bf(v.x);
    o.y = f2bf(v.y);
    *(ushort2*)(featb + (size_t)b * IN_ + c2) = o;
}

// ---------------- gating: LDS histograms, zero global atomics ----------------
__global__ __launch_bounds__(256) void gate_kernel(const float* __restrict__ x, const float* __restrict__ gk,
                                                   int* __restrict__ top4p, float* __restrict__ w6,
                                                   int* __restrict__ task_id, int* __restrict__ tpp,
                                                   int* __restrict__ bct_e, int* __restrict__ bct_t) {
    __shared__ float sgk[T_ * E_];
    __shared__ int hist[E_];
    __shared__ int thist[T_];
    int blk = blockIdx.x, tid = threadIdx.x;
    int b = blk * 256 + tid;
    if (tid < T_ * E_) sgk[tid] = gk[tid];
    if (tid < E_) hist[tid] = 0;
    if (tid < T_) thist[tid] = 0;
    __syncthreads();
    float tv[T_];
#pragma unroll
    for (int i = 0; i < T_; ++i) tv[i] = x[(size_t)b * XROW + IN_ + i];
    float lg[E_];
#pragma unroll
    for (int e = 0; e < E_; ++e) {
        float s = 0.f;
#pragma unroll
        for (int i = 0; i < T_; ++i) s += tv[i] * sgk[i * E_ + e];
        lg[e] = s;
    }
    int idx[K_]; float val[K_];
#pragma unroll
    for (int k = 0; k < K_; ++k) {
        int bi = 0; float bv = -1e30f;
#pragma unroll
        for (int e = 0; e < E_; ++e)
            if (lg[e] > bv) { bv = lg[e]; bi = e; }
        idx[k] = bi; val[k] = bv; lg[bi] = -1e30f;
    }
    float m = val[0];
    float ex[K_]; float s = 0.f;
#pragma unroll
    for (int k = 0; k < K_; ++k) { ex[k] = expf(val[k] - m); s += ex[k]; }
    float inv = 1.f / s;
#pragma unroll
    for (int k = 0; k < K_; ++k) {
        int lp = atomicAdd(&hist[idx[k]], 1);
        top4p[b * K_ + k] = idx[k] | (lp << 8);
        w6[b * 6 + k] = ex[k] * inv;
    }
    w6[b * 6 + 4] = 0.5f;
    w6[b * 6 + 5] = 0.5f;
    int ti = 0; float tb = tv[0];
#pragma unroll
    for (int i = 1; i < T_; ++i)
        if (tv[i] > tb) { tb = tv[i]; ti = i; }
    task_id[b] = ti;
    tpp[b] = atomicAdd(&thist[ti], 1);
    __syncthreads();
    if (tid < E_) bct_e[blk * E_ + tid] = hist[tid];
    if (tid < T_) bct_t[blk * T_ + tid] = thist[tid];
}

// ---------------- table build ----------------
__global__ void build_tables(const int* __restrict__ bct_e, const int* __restrict__ bct_t,
                             int* __restrict__ meta, int* __restrict__ blockbase,
                             int* __restrict__ tblockbase) {
    __shared__ int cnt_s[E_], tcnt_s[T_], base_s[E_], pb_s[T_];
    int tid = threadIdx.x;
    if (tid < E_) {
        int s = 0;
        for (int blk = 0; blk < GB_; ++blk) s += bct_e[blk * E_ + tid];
        cnt_s[tid] = s;
        meta[tid] = s;
    }
    if (tid >= 32 && tid < 32 + T_) {
        int t = tid - 32;
        int s = 0;
        for (int blk = 0; blk < GB_; ++blk) s += bct_t[blk * T_ + t];
        tcnt_s[t] = s;
        meta[91 + t] = s;
    }
    __syncthreads();
    if (tid == 0) {
        int a = 0;
        for (int e = 0; e < E_; ++e) { base_s[e] = a; meta[16 + e] = a; a += cnt_s[e]; }
        int t = 0;
        for (int g = 0; g < 18; ++g) { meta[48 + g] = t; int c = (g < 16) ? cnt_s[g] : B_; t += (c + 127) >> 7; }
        meta[66] = t;
        int pr = 0, br = 0;
        for (int i = 0; i < T_; ++i) {
            pb_s[i] = pr;
            meta[70 + i] = pr;
            meta[80 + i] = br;
            pr += ((tcnt_s[i] + 3) >> 2) << 2;
            br += (tcnt_s[i] + 3) >> 2;
        }
        meta[90] = br;
    }
    __syncthreads();
    if (tid < E_) {
        int run = base_s[tid];
        for (int blk = 0; blk < GB_; ++blk) { blockbase[blk * E_ + tid] = run; run += bct_e[blk * E_ + tid]; }
    }
    if (tid >= 32 && tid < 32 + T_) {
        int t = tid - 32;
        int run = pb_s[t];
        for (int blk = 0; blk < GB_; ++blk) { tblockbase[blk * T_ + t] = run; run += bct_t[blk * T_ + t]; }
    }
}

// ---------------- scatter: pure writes ----------------
__global__ __launch_bounds__(256) void scatter_kernel(const int* __restrict__ top4p,
                                                      const int* __restrict__ blockbase,
                                                      const int* __restrict__ task_id, const int* __restrict__ tpp,
                                                      const int* __restrict__ tblockbase,
                                                      int* __restrict__ pair_sample, int* __restrict__ pair_dst,
                                                      int* __restrict__ torder) {
    int blk = blockIdx.x, tid = threadIdx.x;
    int b = blk * 256 + tid;
#pragma unroll
    for (int k = 0; k < K_; ++k) {
        int v = top4p[b * K_ + k];
        int e = v & 0xFF, lp = v >> 8;
        int p = blockbase[blk * E_ + e] + lp;
        pair_sample[p] = b;
        pair_dst[p] = b * 6 + k;
    }
    pair_sample[B_ * K_ + b] = b;       pair_dst[B_ * K_ + b] = b * 6 + 4;
    pair_sample[B_ * K_ + B_ + b] = b;  pair_dst[B_ * K_ + B_ + b] = b * 6 + 5;
    torder[tblockbase[blk * T_ + task_id[b]] + tpp[b]] = b;
}

// ---------------- plain fp32 -> bf16 convert (hk) ----------------
__global__ __launch_bounds__(256) void convbf16(const float* __restrict__ in, u16* __restrict__ out) {
    int i = blockIdx.x * 256 + threadIdx.x;
    float4 v = ((const float4*)in)[i];
    ushort4 o;
    o.x = f2bf(v.x); o.y = f2bf(v.y); o.z = f2bf(v.z); o.w = f2bf(v.w);
    ((ushort4*)out)[i] = o;
}

// ------------- transpose-convert: fp32 [K][N] -> bf16 [N][K], 64k x 32n tiles, 16B stores -------------
__global__ __launch_bounds__(256) void transconv3(const float* __restrict__ srcA, const float* __restrict__ srcB,
                                                  int splitZ, u16* __restrict__ out, int K, int N) {
    __shared__ float tile[64][33];
    int z = blockIdx.z;
    const float* src = (z < splitZ) ? (srcA + (size_t)z * K * N) : (srcB + (size_t)(z - splitZ) * K * N);
    int k0 = blockIdx.y * 64, n0 = blockIdx.x * 32;
    int tid = threadIdx.x;
    int r = tid >> 2, c8 = (tid & 3) * 8;
    const float* s0 = src + (size_t)(k0 + r) * N + n0 + c8;
    float4 v0 = *(const float4*)s0;
    float4 v1 = *(const float4*)(s0 + 4);
    tile[r][c8 + 0] = v0.x; tile[r][c8 + 1] = v0.y; tile[r][c8 + 2] = v0.z; tile[r][c8 + 3] = v0.w;
    tile[r][c8 + 4] = v1.x; tile[r][c8 + 5] = v1.y; tile[r][c8 + 6] = v1.z; tile[r][c8 + 7] = v1.w;
    __syncthreads();
    int n = tid >> 3, kc = (tid & 7) * 8;
    u16 o[8];
#pragma unroll
    for (int j = 0; j < 8; ++j) o[j] = f2bf(tile[kc + j][n]);
    *(bf16x8*)(out + (size_t)z * N * K + (size_t)(n0 + n) * K + k0 + kc) = *(const bf16x8*)o;
}

// ------------- L1 GEMM: BM=128 BN=128 BK=32, 2-buf 32KB, one barrier/K-step (safe minimal) -------------
// Race kit (R10/R12 lessons), minimal form: bottom wait = vmcnt(0) *lgkmcnt(0)* with "memory"
// (drains this wave's ds_reads before the rendezvous — ds_reads can't cross the asm, so their
// data is sampled before any overwrite). MFMAs may sink below the barrier: harmless, operands are
// registers. Fences bracket the barrier. NO sched_barrier (R13: pinning = -20%).
template <int K, int LAYER>
__global__ __launch_bounds__(256, 4) void gemm9(const u16* __restrict__ Asrc, const u16* __restrict__ wT,
                                                const float* __restrict__ rbias, const float* __restrict__ sbias,
                                                const int* __restrict__ pair_sample, const int* __restrict__ pair_dst,
                                                const int* __restrict__ meta, u16* __restrict__ outp) {
    __shared__ char lds[32768];   // buf b at b*16384: A [128][64B] @0, B [128][64B] @8192 ; C restage reuses all
    const int* tpre = meta + 48;
    const int nwg = tpre[18] * 8;
    int p = blockIdx.x;
    if (p >= nwg) return;
    int q = nwg >> 3, r8 = nwg & 7;
    int xcd = p & 7, iofs = p >> 3;
    int lid = (xcd < r8 ? xcd * (q + 1) : r8 * (q + 1) + (xcd - r8) * q) + iofs;
    int mtu = lid >> 3, nt = lid & 7;
    int e = 0;
    while (mtu >= tpre[e + 1]) ++e;
    int mt = mtu - tpre[e];
    int off, cnt;
    if (e < E_) { off = meta[16 + e]; cnt = meta[e]; }
    else        { off = B_ * K_ + (e - E_) * B_; cnt = B_; }

    const int tid = threadIdx.x;
    const int srow = tid >> 2, sslot = tid & 3;
    const u16* wTe = wT + (size_t)e * W_ * K;
    const u16* ab[2];
    const u16* bb[2];
#pragma unroll
    for (int r = 0; r < 2; ++r) {
        int row = r * 64 + srow;
        int gchunk = sslot ^ ((row >> 1) & 3);
        int gm = mt * 128 + row;
        if (gm >= cnt) gm = cnt - 1;
        int arow = (LAYER == 1) ? pair_sample[off + gm] : (off + gm);
        ab[r] = Asrc + (size_t)arow * K + gchunk * 8;
        bb[r] = wTe + (size_t)(nt * 128 + row) * K + gchunk * 8;
    }

    auto STAGE = [&](int kt, int buf) {
        char* base = lds + buf * 16384;
        GLL16(ab[0] + kt * 32, base + tid * 16);
        GLL16(ab[1] + kt * 32, base + 4096 + tid * 16);
        GLL16(bb[0] + kt * 32, base + 8192 + tid * 16);
        GLL16(bb[1] + kt * 32, base + 12288 + tid * 16);
    };

    f32x4 acc[4][4];
#pragma unroll
    for (int i = 0; i < 4; ++i)
#pragma unroll
        for (int j = 0; j < 4; ++j) acc[i][j] = (f32x4){0.f, 0.f, 0.f, 0.f};

    const int lane = tid & 63, wid = tid >> 6;
    const int wr = wid >> 1, wc = wid & 1;             // wave tile 64x64
    const int fr = lane & 15;
    const int fkb = (lane >> 4) * 16;

    constexpr int NKT = K / 32;
    STAGE(0, 0);
    asm volatile("s_waitcnt vmcnt(0)" ::: "memory");
    __builtin_amdgcn_s_barrier();
    asm volatile("" ::: "memory");
    int cur = 0;
    for (int kt = 0; kt < NKT; ++kt) {
        if (kt + 1 < NKT) STAGE(kt + 1, cur ^ 1);      // buf last read at kt-1, barrier-protected
        char* A = lds + cur * 16384;
        char* Bv = A + 8192;
        bf16x8 af[4], bf[4];
#pragma unroll
        for (int i = 0; i < 4; ++i) {
            int arow = wr * 64 + i * 16 + fr;
            af[i] = *(const bf16x8*)(A + arow * 64 + (fkb ^ (((arow >> 1) & 3) << 4)));
            int brow = wc * 64 + i * 16 + fr;
            bf[i] = *(const bf16x8*)(Bv + brow * 64 + (fkb ^ (((brow >> 1) & 3) << 4)));
        }
#pragma unroll
        for (int i = 0; i < 4; ++i)
#pragma unroll
            for (int j = 0; j < 4; ++j)
                acc[i][j] = __builtin_amdgcn_mfma_f32_16x16x32_bf16(af[i], bf[j], acc[i][j], 0, 0, 0);
        // drain BOTH pipes before rendezvous: vmcnt (stage landed) + lgkmcnt (my ds_reads sampled)
        asm volatile("s_waitcnt vmcnt(0) lgkmcnt(0)" ::: "memory");
        __builtin_amdgcn_s_barrier();
        asm volatile("" ::: "memory");
        cur ^= 1;
    }

    const float* bias = (e < E_) ? (rbias + (size_t)e * W_) : (sbias + (size_t)(e - E_) * W_);
#pragma unroll
    for (int i = 0; i < 4; ++i) {
#pragma unroll
        for (int reg = 0; reg < 4; ++reg) {
            int r = wr * 64 + i * 16 + (lane >> 4) * 4 + reg;
#pragma unroll
            for (int j = 0; j < 4; ++j) {
                int c = wc * 64 + j * 16 + fr;
                float v = acc[i][j][reg] + bias[nt * 128 + c];
                *(u16*)(lds + r * 256 + ((c * 2) ^ ((r & 7) << 4))) = f2bf(fmaxf(v, 0.f));
            }
        }
    }
    __syncthreads();
#pragma unroll
    for (int rr = 0; rr < 8; ++rr) {
        int flat = rr * 4096 + tid * 16;
        int r = flat >> 8;
        int co = flat & 255;
        int m = mt * 128 + r;
        if (m < cnt) {
            int outrow = (LAYER == 1) ? (off + m) : pair_dst[off + m];
            bf16x8 v = *(const bf16x8*)(lds + r * 256 + (co ^ ((r & 7) << 4)));
            *(bf16x8*)(outp + (size_t)outrow * W_ + nt * 128 + (co >> 1)) = v;
        }
    }
}

// ------------- L2 GEMM: R8's m97 structure verbatim — BK=64 single 32KB buffer, 4 blocks/CU -------------
template <int K, int LAYER>
__global__ __launch_bounds__(256, 4) void gemm4(const u16* __restrict__ Asrc, const u16* __restrict__ wT,
                                                const float* __restrict__ rbias, const float* __restrict__ sbias,
                                                const int* __restrict__ pair_sample, const int* __restrict__ pair_dst,
                                                const int* __restrict__ meta, u16* __restrict__ outp) {
    __shared__ char lds[32768];   // A [128][128B swz] @0, B @16384 ; reused for C restage
    const int* tpre = meta + 48;
    const int nwg = tpre[18] * 8;
    int p = blockIdx.x;
    if (p >= nwg) return;
    int q = nwg >> 3, r8 = nwg & 7;
    int xcd = p & 7, iofs = p >> 3;
    int lid = (xcd < r8 ? xcd * (q + 1) : r8 * (q + 1) + (xcd - r8) * q) + iofs;
    int mtu = lid >> 3, nt = lid & 7;
    int e = 0;
    while (mtu >= tpre[e + 1]) ++e;
    int mt = mtu - tpre[e];
    int off, cnt;
    if (e < E_) { off = meta[16 + e]; cnt = meta[e]; }
    else        { off = B_ * K_ + (e - E_) * B_; cnt = B_; }

    const int tid = threadIdx.x;
    const int srow = tid >> 3, sc = tid & 7;
    const u16* wTe = wT + (size_t)e * W_ * K;
    const u16* ab[4];
    const u16* bb[4];
#pragma unroll
    for (int r = 0; r < 4; ++r) {
        int row = r * 32 + srow;
        int swz = (sc ^ (row & 7)) * 8;
        int gm = mt * 128 + row;
        if (gm >= cnt) gm = cnt - 1;
        int arow = (LAYER == 1) ? pair_sample[off + gm] : (off + gm);
        ab[r] = Asrc + (size_t)arow * K + swz;
        bb[r] = wTe + (size_t)(nt * 128 + row) * K + swz;
    }

    f32x4 acc[4][4];
#pragma unroll
    for (int i = 0; i < 4; ++i)
#pragma unroll
        for (int j = 0; j < 4; ++j) acc[i][j] = (f32x4){0.f, 0.f, 0.f, 0.f};

    const int lane = tid & 63, wid = tid >> 6;
    const int wr = wid >> 1, wc = wid & 1;
    const int fr = lane & 15;
    const int fkb = (lane >> 4) * 16;

    constexpr int NKT = K / 64;
    for (int kt = 0; kt < NKT; ++kt) {
#pragma unroll
        for (int r = 0; r < 4; ++r) GLL16(ab[r] + kt * 64, lds + r * 4096 + tid * 16);
#pragma unroll
        for (int r = 0; r < 4; ++r) GLL16(bb[r] + kt * 64, lds + 16384 + r * 4096 + tid * 16);
        __syncthreads();          // compiler-emitted vmcnt(0) drain; 4 blocks/CU hide it (m97/m114)
#pragma unroll
        for (int kk = 0; kk < 2; ++kk) {
            bf16x8 af[4], bf[4];
#pragma unroll
            for (int i = 0; i < 4; ++i) {
                int arow = wr * 64 + i * 16 + fr;
                af[i] = *(const bf16x8*)(lds + arow * 128 + ((kk * 64 + fkb) ^ ((arow & 7) << 4)));
                int brow = wc * 64 + i * 16 + fr;
                bf[i] = *(const bf16x8*)(lds + 16384 + brow * 128 + ((kk * 64 + fkb) ^ ((brow & 7) << 4)));
            }
#pragma unroll
            for (int i = 0; i < 4; ++i)
#pragma unroll
                for (int j = 0; j < 4; ++j)
                    acc[i][j] = __builtin_amdgcn_mfma_f32_16x16x32_bf16(af[i], bf[j], acc[i][j], 0, 0, 0);
        }
        __syncthreads();          // protect buffer before next stage overwrites
    }

    const float* bias = (e < E_) ? (rbias + (size_t)e * W_) : (sbias + (size_t)(e - E_) * W_);
#pragma unroll
    for (int i = 0; i < 4; ++i) {
#pragma unroll
        for (int reg = 0; reg < 4; ++reg) {
            int r = wr * 64 + i * 16 + (lane >> 4) * 4 + reg;
#pragma unroll
            for (int j = 0; j < 4; ++j) {
                int c = wc * 64 + j * 16 + fr;
                float v = acc[i][j][reg] + bias[nt * 128 + c];
                *(u16*)(lds + r * 256 + ((c * 2) ^ ((r & 7) << 4))) = f2bf(fmaxf(v, 0.f));
            }
        }
    }
    __syncthreads();
#pragma unroll
    for (int rr = 0; rr < 8; ++rr) {
        int flat = rr * 4096 + tid * 16;
        int r = flat >> 8;
        int co = flat & 255;
        int m = mt * 128 + r;
        if (m < cnt) {
            int outrow = (LAYER == 1) ? (off + m) : pair_dst[off + m];
            bf16x8 v = *(const bf16x8*)(lds + r * 256 + (co ^ ((r & 7) << 4)));
            *(bf16x8*)(outp + (size_t)outrow * W_ + nt * 128 + (co >> 1)) = v;
        }
    }
}

// ------------- combine: 4 same-task samples/block; fast-tanh(sum) then head GEMV -------------
__global__ __launch_bounds__(256) void combine4(const u16* __restrict__ h2, const float* __restrict__ w6,
                                                const int* __restrict__ torder, const int* __restrict__ meta,
                                                const u16* __restrict__ hkb, const float* __restrict__ hb,
                                                float* __restrict__ out) {
    __shared__ float f[4][W_];
    __shared__ float partials[4][4][64];
    const int* bp = meta + 80;
    int blk = blockIdx.x;
    if (blk >= bp[T_]) return;
    int t = 0;
    while (blk >= bp[t + 1]) ++t;
    int slot0 = meta[70 + t] + (blk - bp[t]) * 4;
    int vend  = meta[70 + t] + meta[91 + t];
    int tid = threadIdx.x;
    int s0 = torder[slot0];
    int smp[4];
#pragma unroll
    for (int i = 0; i < 4; ++i) {
        int v = torder[slot0 + i];
        smp[i] = (slot0 + i < vend) ? v : s0;
    }
#pragma unroll
    for (int s = 0; s < 4; ++s) {
        int b = smp[s];
        float wsl[6];
#pragma unroll
        for (int qq = 0; qq < 6; ++qq) wsl[qq] = w6[b * 6 + qq];
        float sum[4] = {0.f, 0.f, 0.f, 0.f};
#pragma unroll
        for (int qq = 0; qq < 6; ++qq) {
            ushort4 v = *(const ushort4*)(h2 + (size_t)(b * 6 + qq) * W_ + tid * 4);
            sum[0] += wsl[qq] * bf2f(v.x);
            sum[1] += wsl[qq] * bf2f(v.y);
            sum[2] += wsl[qq] * bf2f(v.z);
            sum[3] += wsl[qq] * bf2f(v.w);
        }
        float4 tf;
        tf.x = fast_tanh(sum[0]); tf.y = fast_tanh(sum[1]);
        tf.z = fast_tanh(sum[2]); tf.w = fast_tanh(sum[3]);
        *(float4*)(&f[s][tid * 4]) = tf;               // single b128 store: conflict-free
    }
    __syncthreads();
    int d = tid & 63, g = tid >> 6;
    const u16* hp = hkb + (size_t)t * W_ * HD_ + d;
    float acc[4] = {0.f, 0.f, 0.f, 0.f};
#pragma unroll 4
    for (int w = g; w < W_; w += 4) {
        float hv = bf2f(hp[(size_t)w * HD_]);
#pragma unroll
        for (int s = 0; s < 4; ++s) acc[s] += f[s][w] * hv;
    }
#pragma unroll
    for (int s = 0; s < 4; ++s) partials[g][s][d] = acc[s];
    __syncthreads();
    int ss = tid >> 6, dd = tid & 63;
    float r = partials[0][ss][dd] + partials[1][ss][dd] + partials[2][ss][dd] + partials[3][ss][dd]
            + hb[t * HD_ + dd];
    out[(size_t)smp[ss] * HD_ + dd] = r;
}

extern "C" void kernel_launch(void* const* d_in, const int* in_sizes, int n_in,
                              void* d_out, int out_size, void* d_ws, size_t ws_size,
                              hipStream_t stream) {
    const float* x   = (const float*)d_in[0];
    const float* gk  = (const float*)d_in[1];
    const float* rk0 = (const float*)d_in[2];
    const float* rb0 = (const float*)d_in[3];
    const float* rk1 = (const float*)d_in[4];
    const float* rb1 = (const float*)d_in[5];
    const float* sk0 = (const float*)d_in[6];
    const float* sb0 = (const float*)d_in[7];
    const float* sk1 = (const float*)d_in[8];
    const float* sb1 = (const float*)d_in[9];
    const float* hk  = (const float*)d_in[10];
    const float* hb  = (const float*)d_in[11];
    float* out = (float*)d_out;
    (void)in_sizes; (void)n_in; (void)out_size; (void)ws_size;

    char* ws = (char*)d_ws;
    size_t o = 0;
    auto alloc = [&](size_t bytes) { char* p = ws + o; o += (bytes + 255) & ~(size_t)255; return p; };
    int* meta        = (int*)alloc(512);
    int* bct_e       = (int*)alloc((size_t)GB_ * E_ * 4);
    int* bct_t       = (int*)alloc((size_t)GB_ * T_ * 4);
    int* blockbase   = (int*)alloc((size_t)GB_ * E_ * 4);
    int* tblockbase  = (int*)alloc((size_t)GB_ * T_ * 4);
    int* top4p       = (int*)alloc((size_t)B_ * K_ * 4);
    float* w6        = (float*)alloc((size_t)B_ * 6 * 4);
    int* task_id     = (int*)alloc((size_t)B_ * 4);
    int* tpp         = (int*)alloc((size_t)B_ * 4);
    int* pair_sample = (int*)alloc((size_t)NPAIR * 4);
    int* pair_dst    = (int*)alloc((size_t)NPAIR * 4);
    int* torder      = (int*)alloc((size_t)(B_ + 64) * 4);
    u16* featb       = (u16*)alloc((size_t)B_ * IN_ * 2);
    u16* w0T         = (u16*)alloc((size_t)(E_ + S_) * W_ * IN_ * 2);
    u16* w1T         = (u16*)alloc((size_t)(E_ + S_) * W_ * W_ * 2);
    u16* hkb         = (u16*)alloc((size_t)T_ * W_ * HD_ * 2);
    u16* h1          = (u16*)alloc((size_t)NPAIR * W_ * 2);
    u16* h2          = (u16*)alloc((size_t)NPAIR * W_ * 2);

    featconv<<<B_, 256, 0, stream>>>(x, featb);
    gate_kernel<<<GB_, 256, 0, stream>>>(x, gk, top4p, w6, task_id, tpp, bct_e, bct_t);
    build_tables<<<1, 64, 0, stream>>>(bct_e, bct_t, meta, blockbase, tblockbase);
    scatter_kernel<<<GB_, 256, 0, stream>>>(top4p, blockbase, task_id, tpp, tblockbase,
                                            pair_sample, pair_dst, torder);
    transconv3<<<dim3(W_ / 32, IN_ / 64, E_ + S_), 256, 0, stream>>>(rk0, sk0, E_, w0T, IN_, W_);
    transconv3<<<dim3(W_ / 32, W_ / 64, E_ + S_), 256, 0, stream>>>(rk1, sk1, E_, w1T, W_, W_);
    convbf16<<<(T_ * W_ * HD_) / 1024, 256, 0, stream>>>(hk, hkb);
    gemm9<IN_, 1><<<GEMM_GRID, 256, 0, stream>>>(featb, w0T, rb0, sb0, pair_sample, pair_dst, meta, h1);
    gemm4<W_, 2><<<GEMM_GRID, 256, 0, stream>>>(h1, w1T, rb1, sb1, pair_sample, pair_dst, meta, h2);
    combine4<<<CB_GRID, 256, 0, stream>>>(h2, w6, torder, meta, hkb, hb, out);
}

// Round 15
// 175.574 us; speedup vs baseline: 1.0980x; 1.0713x over previous
//
#include <hip/hip_runtime.h>

typedef unsigned short u16;
typedef __attribute__((ext_vector_type(8))) short bf16x8;
typedef __attribute__((ext_vector_type(4))) float f32x4;

constexpr int B_ = 4096, IN_ = 512, T_ = 10, E_ = 16, S_ = 2, K_ = 4, W_ = 1024, HD_ = 64;
constexpr int XROW = IN_ + T_;             // 522
constexpr int NPAIR = B_ * (K_ + S_);      // 24576
constexpr int MTU = 208;                   // worst-case sum of ceil(cnt/128) over 18 groups
constexpr int GEMM_GRID = MTU * 8;         // 1664
constexpr int GB_ = 16;                    // gate blocks
constexpr int CB_GRID = 1034;              // worst-case combine blocks (sum ceil(tcnt/4))

// prep kernel block ranges
constexpr int PREP_FEAT = B_;                      // 4096: featconv
constexpr int PREP_TCIN = (W_ / 32) * (IN_ / 64) * (E_ + S_);   // 4608
constexpr int PREP_TCW  = (W_ / 32) * (W_ / 64) * (E_ + S_);    // 9216
constexpr int PREP_CONV = (T_ * W_ * HD_) / 1024;  // 640
constexpr int PREP_GRID = PREP_FEAT + PREP_TCIN + PREP_TCW + PREP_CONV;

// meta (ints): 0 counts_e[16] | 16 bases_e[16] | 48 tprefix128[19]
//            | 70 pb[10] | 80 bp[11] | 91 tcnt[10]

#define GLL16(g, l) __builtin_amdgcn_global_load_lds( \
    (const __attribute__((address_space(1))) void*)(g), \
    (__attribute__((address_space(3))) void*)(l), 16, 0, 0)

__device__ __forceinline__ u16 f2bf(float x) {
    unsigned u = __float_as_uint(x);
    return (u16)((u + 0x7fffu + ((u >> 16) & 1u)) >> 16);
}
__device__ __forceinline__ float bf2f(u16 b) { return __uint_as_float(((unsigned)b) << 16); }

// fast tanh: 1 - 2/(e^{2x}+1); v_exp + v_rcp, saturates correctly at +-1
__device__ __forceinline__ float fast_tanh(float x) {
    float t = __expf(2.f * x);
    return 1.f - 2.f * __builtin_amdgcn_rcpf(t + 1.f);
}

// ---------------- merged prep: featconv | transconv(rk0/sk0) | transconv(rk1/sk1) | convbf16(hk) ----------------
__device__ __forceinline__ void transconv_body(const float* __restrict__ src, u16* __restrict__ outz,
                                               int K, int N, int k0, int n0, int tid, float (*tile)[33]) {
    int r = tid >> 2, c8 = (tid & 3) * 8;
    const float* s0 = src + (size_t)(k0 + r) * N + n0 + c8;
    float4 v0 = *(const float4*)s0;
    float4 v1 = *(const float4*)(s0 + 4);
    tile[r][c8 + 0] = v0.x; tile[r][c8 + 1] = v0.y; tile[r][c8 + 2] = v0.z; tile[r][c8 + 3] = v0.w;
    tile[r][c8 + 4] = v1.x; tile[r][c8 + 5] = v1.y; tile[r][c8 + 6] = v1.z; tile[r][c8 + 7] = v1.w;
    __syncthreads();
    int n = tid >> 3, kc = (tid & 7) * 8;
    u16 o[8];
#pragma unroll
    for (int j = 0; j < 8; ++j) o[j] = f2bf(tile[kc + j][n]);
    *(bf16x8*)(outz + (size_t)(n0 + n) * K + k0 + kc) = *(const bf16x8*)o;
}

__global__ __launch_bounds__(256) void prep(const float* __restrict__ x, u16* __restrict__ featb,
                                            const float* __restrict__ rk0, const float* __restrict__ sk0,
                                            u16* __restrict__ w0T,
                                            const float* __restrict__ rk1, const float* __restrict__ sk1,
                                            u16* __restrict__ w1T,
                                            const float* __restrict__ hk, u16* __restrict__ hkb) {
    __shared__ float tile[64][33];
    int bid = blockIdx.x, tid = threadIdx.x;
    if (bid < PREP_FEAT) {
        int b = bid;
        int c2 = tid * 2;
        float2 v = *(const float2*)(x + (size_t)b * XROW + c2);
        ushort2 o;
        o.x = f2bf(v.x);
        o.y = f2bf(v.y);
        *(ushort2*)(featb + (size_t)b * IN_ + c2) = o;
        return;
    }
    bid -= PREP_FEAT;
    if (bid < PREP_TCIN) {
        int z = bid / ((W_ / 32) * (IN_ / 64));
        int rem = bid % ((W_ / 32) * (IN_ / 64));
        int ky = rem / (W_ / 32), nx = rem % (W_ / 32);
        const float* src = (z < E_) ? (rk0 + (size_t)z * IN_ * W_) : (sk0 + (size_t)(z - E_) * IN_ * W_);
        transconv_body(src, w0T + (size_t)z * W_ * IN_, IN_, W_, ky * 64, nx * 32, tid, tile);
        return;
    }
    bid -= PREP_TCIN;
    if (bid < PREP_TCW) {
        int z = bid / ((W_ / 32) * (W_ / 64));
        int rem = bid % ((W_ / 32) * (W_ / 64));
        int ky = rem / (W_ / 32), nx = rem % (W_ / 32);
        const float* src = (z < E_) ? (rk1 + (size_t)z * W_ * W_) : (sk1 + (size_t)(z - E_) * W_ * W_);
        transconv_body(src, w1T + (size_t)z * W_ * W_, W_, W_, ky * 64, nx * 32, tid, tile);
        return;
    }
    bid -= PREP_TCW;
    {
        int i = bid * 256 + tid;
        float4 v = ((const float4*)hk)[i];
        ushort4 o;
        o.x = f2bf(v.x); o.y = f2bf(v.y); o.z = f2bf(v.z); o.w = f2bf(v.w);
        ((ushort4*)hkb)[i] = o;
    }
}

// ---------------- gating: LDS histograms, zero global atomics ----------------
__global__ __launch_bounds__(256) void gate_kernel(const float* __restrict__ x, const float* __restrict__ gk,
                                                   int* __restrict__ top4p, float* __restrict__ w6,
                                                   int* __restrict__ task_id, int* __restrict__ tpp,
                                                   int* __restrict__ bct_e, int* __restrict__ bct_t) {
    __shared__ float sgk[T_ * E_];
    __shared__ int hist[E_];
    __shared__ int thist[T_];
    int blk = blockIdx.x, tid = threadIdx.x;
    int b = blk * 256 + tid;
    if (tid < T_ * E_) sgk[tid] = gk[tid];
    if (tid < E_) hist[tid] = 0;
    if (tid < T_) thist[tid] = 0;
    __syncthreads();
    float tv[T_];
#pragma unroll
    for (int i = 0; i < T_; ++i) tv[i] = x[(size_t)b * XROW + IN_ + i];
    float lg[E_];
#pragma unroll
    for (int e = 0; e < E_; ++e) {
        float s = 0.f;
#pragma unroll
        for (int i = 0; i < T_; ++i) s += tv[i] * sgk[i * E_ + e];
        lg[e] = s;
    }
    int idx[K_]; float val[K_];
#pragma unroll
    for (int k = 0; k < K_; ++k) {
        int bi = 0; float bv = -1e30f;
#pragma unroll
        for (int e = 0; e < E_; ++e)
            if (lg[e] > bv) { bv = lg[e]; bi = e; }
        idx[k] = bi; val[k] = bv; lg[bi] = -1e30f;
    }
    float m = val[0];
    float ex[K_]; float s = 0.f;
#pragma unroll
    for (int k = 0; k < K_; ++k) { ex[k] = expf(val[k] - m); s += ex[k]; }
    float inv = 1.f / s;
#pragma unroll
    for (int k = 0; k < K_; ++k) {
        int lp = atomicAdd(&hist[idx[k]], 1);
        top4p[b * K_ + k] = idx[k] | (lp << 8);
        w6[b * 6 + k] = ex[k] * inv;
    }
    w6[b * 6 + 4] = 0.5f;
    w6[b * 6 + 5] = 0.5f;
    int ti = 0; float tb = tv[0];
#pragma unroll
    for (int i = 1; i < T_; ++i)
        if (tv[i] > tb) { tb = tv[i]; ti = i; }
    task_id[b] = ti;
    tpp[b] = atomicAdd(&thist[ti], 1);
    __syncthreads();
    if (tid < E_) bct_e[blk * E_ + tid] = hist[tid];
    if (tid < T_) bct_t[blk * T_ + tid] = thist[tid];
}

// ---------------- table build ----------------
__global__ void build_tables(const int* __restrict__ bct_e, const int* __restrict__ bct_t,
                             int* __restrict__ meta, int* __restrict__ blockbase,
                             int* __restrict__ tblockbase) {
    __shared__ int cnt_s[E_], tcnt_s[T_], base_s[E_], pb_s[T_];
    int tid = threadIdx.x;
    if (tid < E_) {
        int s = 0;
        for (int blk = 0; blk < GB_; ++blk) s += bct_e[blk * E_ + tid];
        cnt_s[tid] = s;
        meta[tid] = s;
    }
    if (tid >= 32 && tid < 32 + T_) {
        int t = tid - 32;
        int s = 0;
        for (int blk = 0; blk < GB_; ++blk) s += bct_t[blk * T_ + t];
        tcnt_s[t] = s;
        meta[91 + t] = s;
    }
    __syncthreads();
    if (tid == 0) {
        int a = 0;
        for (int e = 0; e < E_; ++e) { base_s[e] = a; meta[16 + e] = a; a += cnt_s[e]; }
        int t = 0;
        for (int g = 0; g < 18; ++g) { meta[48 + g] = t; int c = (g < 16) ? cnt_s[g] : B_; t += (c + 127) >> 7; }
        meta[66] = t;
        int pr = 0, br = 0;
        for (int i = 0; i < T_; ++i) {
            pb_s[i] = pr;
            meta[70 + i] = pr;
            meta[80 + i] = br;
            pr += ((tcnt_s[i] + 3) >> 2) << 2;
            br += (tcnt_s[i] + 3) >> 2;
        }
        meta[90] = br;
    }
    __syncthreads();
    if (tid < E_) {
        int run = base_s[tid];
        for (int blk = 0; blk < GB_; ++blk) { blockbase[blk * E_ + tid] = run; run += bct_e[blk * E_ + tid]; }
    }
    if (tid >= 32 && tid < 32 + T_) {
        int t = tid - 32;
        int run = pb_s[t];
        for (int blk = 0; blk < GB_; ++blk) { tblockbase[blk * T_ + t] = run; run += bct_t[blk * T_ + t]; }
    }
}

// ---------------- scatter: pure writes ----------------
__global__ __launch_bounds__(256) void scatter_kernel(const int* __restrict__ top4p,
                                                      const int* __restrict__ blockbase,
                                                      const int* __restrict__ task_id, const int* __restrict__ tpp,
                                                      const int* __restrict__ tblockbase,
                                                      int* __restrict__ pair_sample, int* __restrict__ pair_dst,
                                                      int* __restrict__ torder) {
    int blk = blockIdx.x, tid = threadIdx.x;
    int b = blk * 256 + tid;
#pragma unroll
    for (int k = 0; k < K_; ++k) {
        int v = top4p[b * K_ + k];
        int e = v & 0xFF, lp = v >> 8;
        int p = blockbase[blk * E_ + e] + lp;
        pair_sample[p] = b;
        pair_dst[p] = b * 6 + k;
    }
    pair_sample[B_ * K_ + b] = b;       pair_dst[B_ * K_ + b] = b * 6 + 4;
    pair_sample[B_ * K_ + B_ + b] = b;  pair_dst[B_ * K_ + B_ + b] = b * 6 + 5;
    torder[tblockbase[blk * T_ + task_id[b]] + tpp[b]] = b;
}

// ------------- L1 GEMM: BM=128 BN=128 BK=32, 2-buf 32KB, one barrier/K-step (safe minimal) -------------
// Race kit (R10/R12): bottom wait = vmcnt(0) lgkmcnt(0) with "memory"; fences bracket the raw
// barrier; NO sched_barrier (R13: pinning = -20%).
template <int K, int LAYER>
__global__ __launch_bounds__(256, 4) void gemm9(const u16* __restrict__ Asrc, const u16* __restrict__ wT,
                                                const float* __restrict__ rbias, const float* __restrict__ sbias,
                                                const int* __restrict__ pair_sample, const int* __restrict__ pair_dst,
                                                const int* __restrict__ meta, u16* __restrict__ outp) {
    __shared__ char lds[32768];   // buf b at b*16384: A [128][64B] @0, B [128][64B] @8192 ; C restage reuses all
    const int* tpre = meta + 48;
    const int nwg = tpre[18] * 8;
    int p = blockIdx.x;
    if (p >= nwg) return;
    int q = nwg >> 3, r8 = nwg & 7;
    int xcd = p & 7, iofs = p >> 3;
    int lid = (xcd < r8 ? xcd * (q + 1) : r8 * (q + 1) + (xcd - r8) * q) + iofs;
    int mtu = lid >> 3, nt = lid & 7;
    int e = 0;
    while (mtu >= tpre[e + 1]) ++e;
    int mt = mtu - tpre[e];
    int off, cnt;
    if (e < E_) { off = meta[16 + e]; cnt = meta[e]; }
    else        { off = B_ * K_ + (e - E_) * B_; cnt = B_; }

    const int tid = threadIdx.x;
    const int srow = tid >> 2, sslot = tid & 3;
    const u16* wTe = wT + (size_t)e * W_ * K;
    const u16* ab[2];
    const u16* bb[2];
#pragma unroll
    for (int r = 0; r < 2; ++r) {
        int row = r * 64 + srow;
        int gchunk = sslot ^ ((row >> 1) & 3);
        int gm = mt * 128 + row;
        if (gm >= cnt) gm = cnt - 1;
        int arow = (LAYER == 1) ? pair_sample[off + gm] : (off + gm);
        ab[r] = Asrc + (size_t)arow * K + gchunk * 8;
        bb[r] = wTe + (size_t)(nt * 128 + row) * K + gchunk * 8;
    }

    auto STAGE = [&](int kt, int buf) {
        char* base = lds + buf * 16384;
        GLL16(ab[0] + kt * 32, base + tid * 16);
        GLL16(ab[1] + kt * 32, base + 4096 + tid * 16);
        GLL16(bb[0] + kt * 32, base + 8192 + tid * 16);
        GLL16(bb[1] + kt * 32, base + 12288 + tid * 16);
    };

    f32x4 acc[4][4];
#pragma unroll
    for (int i = 0; i < 4; ++i)
#pragma unroll
        for (int j = 0; j < 4; ++j) acc[i][j] = (f32x4){0.f, 0.f, 0.f, 0.f};

    const int lane = tid & 63, wid = tid >> 6;
    const int wr = wid >> 1, wc = wid & 1;             // wave tile 64x64
    const int fr = lane & 15;
    const int fkb = (lane >> 4) * 16;

    constexpr int NKT = K / 32;
    STAGE(0, 0);
    asm volatile("s_waitcnt vmcnt(0)" ::: "memory");
    __builtin_amdgcn_s_barrier();
    asm volatile("" ::: "memory");
    int cur = 0;
    for (int kt = 0; kt < NKT; ++kt) {
        if (kt + 1 < NKT) STAGE(kt + 1, cur ^ 1);      // buf last read at kt-1, barrier-protected
        char* A = lds + cur * 16384;
        char* Bv = A + 8192;
        bf16x8 af[4], bf[4];
#pragma unroll
        for (int i = 0; i < 4; ++i) {
            int arow = wr * 64 + i * 16 + fr;
            af[i] = *(const bf16x8*)(A + arow * 64 + (fkb ^ (((arow >> 1) & 3) << 4)));
            int brow = wc * 64 + i * 16 + fr;
            bf[i] = *(const bf16x8*)(Bv + brow * 64 + (fkb ^ (((brow >> 1) & 3) << 4)));
        }
#pragma unroll
        for (int i = 0; i < 4; ++i)
#pragma unroll
            for (int j = 0; j < 4; ++j)
                acc[i][j] = __builtin_amdgcn_mfma_f32_16x16x32_bf16(af[i], bf[j], acc[i][j], 0, 0, 0);
        asm volatile("s_waitcnt vmcnt(0) lgkmcnt(0)" ::: "memory");
        __builtin_amdgcn_s_barrier();
        asm volatile("" ::: "memory");
        cur ^= 1;
    }

    const float* bias = (e < E_) ? (rbias + (size_t)e * W_) : (sbias + (size_t)(e - E_) * W_);
#pragma unroll
    for (int i = 0; i < 4; ++i) {
#pragma unroll
        for (int reg = 0; reg < 4; ++reg) {
            int r = wr * 64 + i * 16 + (lane >> 4) * 4 + reg;
#pragma unroll
            for (int j = 0; j < 4; ++j) {
                int c = wc * 64 + j * 16 + fr;
                float v = acc[i][j][reg] + bias[nt * 128 + c];
                *(u16*)(lds + r * 256 + ((c * 2) ^ ((r & 7) << 4))) = f2bf(fmaxf(v, 0.f));
            }
        }
    }
    __syncthreads();
#pragma unroll
    for (int rr = 0; rr < 8; ++rr) {
        int flat = rr * 4096 + tid * 16;
        int r = flat >> 8;
        int co = flat & 255;
        int m = mt * 128 + r;
        if (m < cnt) {
            int outrow = (LAYER == 1) ? (off + m) : pair_dst[off + m];
            bf16x8 v = *(const bf16x8*)(lds + r * 256 + (co ^ ((r & 7) << 4)));
            *(bf16x8*)(outp + (size_t)outrow * W_ + nt * 128 + (co >> 1)) = v;
        }
    }
}

// ------------- L2 GEMM: m97 structure — BK=64 single 32KB buffer, 4 blocks/CU -------------
template <int K, int LAYER>
__global__ __launch_bounds__(256, 4) void gemm4(const u16* __restrict__ Asrc, const u16* __restrict__ wT,
                                                const float* __restrict__ rbias, const float* __restrict__ sbias,
                                                const int* __restrict__ pair_sample, const int* __restrict__ pair_dst,
                                                const int* __restrict__ meta, u16* __restrict__ outp) {
    __shared__ char lds[32768];   // A [128][128B swz] @0, B @16384 ; reused for C restage
    const int* tpre = meta + 48;
    const int nwg = tpre[18] * 8;
    int p = blockIdx.x;
    if (p >= nwg) return;
    int q = nwg >> 3, r8 = nwg & 7;
    int xcd = p & 7, iofs = p >> 3;
    int lid = (xcd < r8 ? xcd * (q + 1) : r8 * (q + 1) + (xcd - r8) * q) + iofs;
    int mtu = lid >> 3, nt = lid & 7;
    int e = 0;
    while (mtu >= tpre[e + 1]) ++e;
    int mt = mtu - tpre[e];
    int off, cnt;
    if (e < E_) { off = meta[16 + e]; cnt = meta[e]; }
    else        { off = B_ * K_ + (e - E_) * B_; cnt = B_; }

    const int tid = threadIdx.x;
    const int srow = tid >> 3, sc = tid & 7;
    const u16* wTe = wT + (size_t)e * W_ * K;
    const u16* ab[4];
    const u16* bb[4];
#pragma unroll
    for (int r = 0; r < 4; ++r) {
        int row = r * 32 + srow;
        int swz = (sc ^ (row & 7)) * 8;
        int gm = mt * 128 + row;
        if (gm >= cnt) gm = cnt - 1;
        int arow = (LAYER == 1) ? pair_sample[off + gm] : (off + gm);
        ab[r] = Asrc + (size_t)arow * K + swz;
        bb[r] = wTe + (size_t)(nt * 128 + row) * K + swz;
    }

    f32x4 acc[4][4];
#pragma unroll
    for (int i = 0; i < 4; ++i)
#pragma unroll
        for (int j = 0; j < 4; ++j) acc[i][j] = (f32x4){0.f, 0.f, 0.f, 0.f};

    const int lane = tid & 63, wid = tid >> 6;
    const int wr = wid >> 1, wc = wid & 1;
    const int fr = lane & 15;
    const int fkb = (lane >> 4) * 16;

    constexpr int NKT = K / 64;
    for (int kt = 0; kt < NKT; ++kt) {
#pragma unroll
        for (int r = 0; r < 4; ++r) GLL16(ab[r] + kt * 64, lds + r * 4096 + tid * 16);
#pragma unroll
        for (int r = 0; r < 4; ++r) GLL16(bb[r] + kt * 64, lds + 16384 + r * 4096 + tid * 16);
        __syncthreads();          // compiler-emitted vmcnt(0) drain; 4 blocks/CU hide it (m97/m114)
#pragma unroll
        for (int kk = 0; kk < 2; ++kk) {
            bf16x8 af[4], bf[4];
#pragma unroll
            for (int i = 0; i < 4; ++i) {
                int arow = wr * 64 + i * 16 + fr;
                af[i] = *(const bf16x8*)(lds + arow * 128 + ((kk * 64 + fkb) ^ ((arow & 7) << 4)));
                int brow = wc * 64 + i * 16 + fr;
                bf[i] = *(const bf16x8*)(lds + 16384 + brow * 128 + ((kk * 64 + fkb) ^ ((brow & 7) << 4)));
            }
#pragma unroll
            for (int i = 0; i < 4; ++i)
#pragma unroll
                for (int j = 0; j < 4; ++j)
                    acc[i][j] = __builtin_amdgcn_mfma_f32_16x16x32_bf16(af[i], bf[j], acc[i][j], 0, 0, 0);
        }
        __syncthreads();          // protect buffer before next stage overwrites
    }

    const float* bias = (e < E_) ? (rbias + (size_t)e * W_) : (sbias + (size_t)(e - E_) * W_);
#pragma unroll
    for (int i = 0; i < 4; ++i) {
#pragma unroll
        for (int reg = 0; reg < 4; ++reg) {
            int r = wr * 64 + i * 16 + (lane >> 4) * 4 + reg;
#pragma unroll
            for (int j = 0; j < 4; ++j) {
                int c = wc * 64 + j * 16 + fr;
                float v = acc[i][j][reg] + bias[nt * 128 + c];
                *(u16*)(lds + r * 256 + ((c * 2) ^ ((r & 7) << 4))) = f2bf(fmaxf(v, 0.f));
            }
        }
    }
    __syncthreads();
#pragma unroll
    for (int rr = 0; rr < 8; ++rr) {
        int flat = rr * 4096 + tid * 16;
        int r = flat >> 8;
        int co = flat & 255;
        int m = mt * 128 + r;
        if (m < cnt) {
            int outrow = (LAYER == 1) ? (off + m) : pair_dst[off + m];
            bf16x8 v = *(const bf16x8*)(lds + r * 256 + (co ^ ((r & 7) << 4)));
            *(bf16x8*)(outp + (size_t)outrow * W_ + nt * 128 + (co >> 1)) = v;
        }
    }
}

// ------------- combine: 4 same-task samples/block; fast-tanh(sum) then head GEMV -------------
__global__ __launch_bounds__(256) void combine4(const u16* __restrict__ h2, const float* __restrict__ w6,
                                                const int* __restrict__ torder, const int* __restrict__ meta,
                                                const u16* __restrict__ hkb, const float* __restrict__ hb,
                                                float* __restrict__ out) {
    __shared__ float f[4][W_];
    __shared__ float partials[4][4][64];
    const int* bp = meta + 80;
    int blk = blockIdx.x;
    if (blk >= bp[T_]) return;
    int t = 0;
    while (blk >= bp[t + 1]) ++t;
    int slot0 = meta[70 + t] + (blk - bp[t]) * 4;
    int vend  = meta[70 + t] + meta[91 + t];
    int tid = threadIdx.x;
    int s0 = torder[slot0];
    int smp[4];
#pragma unroll
    for (int i = 0; i < 4; ++i) {
        int v = torder[slot0 + i];
        smp[i] = (slot0 + i < vend) ? v : s0;
    }
#pragma unroll
    for (int s = 0; s < 4; ++s) {
        int b = smp[s];
        float wsl[6];
#pragma unroll
        for (int qq = 0; qq < 6; ++qq) wsl[qq] = w6[b * 6 + qq];
        float sum[4] = {0.f, 0.f, 0.f, 0.f};
#pragma unroll
        for (int qq = 0; qq < 6; ++qq) {
            ushort4 v = *(const ushort4*)(h2 + (size_t)(b * 6 + qq) * W_ + tid * 4);
            sum[0] += wsl[qq] * bf2f(v.x);
            sum[1] += wsl[qq] * bf2f(v.y);
            sum[2] += wsl[qq] * bf2f(v.z);
            sum[3] += wsl[qq] * bf2f(v.w);
        }
        float4 tf;
        tf.x = fast_tanh(sum[0]); tf.y = fast_tanh(sum[1]);
        tf.z = fast_tanh(sum[2]); tf.w = fast_tanh(sum[3]);
        *(float4*)(&f[s][tid * 4]) = tf;               // single b128 store: conflict-free
    }
    __syncthreads();
    int d = tid & 63, g = tid >> 6;
    const u16* hp = hkb + (size_t)t * W_ * HD_ + d;
    float acc[4] = {0.f, 0.f, 0.f, 0.f};
#pragma unroll 4
    for (int w = g; w < W_; w += 4) {
        float hv = bf2f(hp[(size_t)w * HD_]);
#pragma unroll
        for (int s = 0; s < 4; ++s) acc[s] += f[s][w] * hv;
    }
#pragma unroll
    for (int s = 0; s < 4; ++s) partials[g][s][d] = acc[s];
    __syncthreads();
    int ss = tid >> 6, dd = tid & 63;
    float r = partials[0][ss][dd] + partials[1][ss][dd] + partials[2][ss][dd] + partials[3][ss][dd]
            + hb[t * HD_ + dd];
    out[(size_t)smp[ss] * HD_ + dd] = r;
}

extern "C" void kernel_launch(void* const* d_in, const int* in_sizes, int n_in,
                              void* d_out, int out_size, void* d_ws, size_t ws_size,
                              hipStream_t stream) {
    const float* x   = (const float*)d_in[0];
    const float* gk  = (const float*)d_in[1];
    const float* rk0 = (const float*)d_in[2];
    const float* rb0 = (const float*)d_in[3];
    const float* rk1 = (const float*)d_in[4];
    const float* rb1 = (const float*)d_in[5];
    const float* sk0 = (const float*)d_in[6];
    const float* sb0 = (const float*)d_in[7];
    const float* sk1 = (const float*)d_in[8];
    const float* sb1 = (const float*)d_in[9];
    const float* hk  = (const float*)d_in[10];
    const float* hb  = (const float*)d_in[11];
    float* out = (float*)d_out;
    (void)in_sizes; (void)n_in; (void)out_size; (void)ws_size;

    char* ws = (char*)d_ws;
    size_t o = 0;
    auto alloc = [&](size_t bytes) { char* p = ws + o; o += (bytes + 255) & ~(size_t)255; return p; };
    int* meta        = (int*)alloc(512);
    int* bct_e       = (int*)alloc((size_t)GB_ * E_ * 4);
    int* bct_t       = (int*)alloc((size_t)GB_ * T_ * 4);
    int* blockbase   = (int*)alloc((size_t)GB_ * E_ * 4);
    int* tblockbase  = (int*)alloc((size_t)GB_ * T_ * 4);
    int* top4p       = (int*)alloc((size_t)B_ * K_ * 4);
    float* w6        = (float*)alloc((size_t)B_ * 6 * 4);
    int* task_id     = (int*)alloc((size_t)B_ * 4);
    int* tpp         = (int*)alloc((size_t)B_ * 4);
    int* pair_sample = (int*)alloc((size_t)NPAIR * 4);
    int* pair_dst    = (int*)alloc((size_t)NPAIR * 4);
    int* torder      = (int*)alloc((size_t)(B_ + 64) * 4);
    u16* featb       = (u16*)alloc((size_t)B_ * IN_ * 2);
    u16* w0T         = (u16*)alloc((size_t)(E_ + S_) * W_ * IN_ * 2);
    u16* w1T         = (u16*)alloc((size_t)(E_ + S_) * W_ * W_ * 2);
    u16* hkb         = (u16*)alloc((size_t)T_ * W_ * HD_ * 2);
    u16* h1          = (u16*)alloc((size_t)NPAIR * W_ * 2);
    u16* h2          = (u16*)alloc((size_t)NPAIR * W_ * 2);

    prep<<<PREP_GRID, 256, 0, stream>>>(x, featb, rk0, sk0, w0T, rk1, sk1, w1T, hk, hkb);
    gate_kernel<<<GB_, 256, 0, stream>>>(x, gk, top4p, w6, task_id, tpp, bct_e, bct_t);
    build_tables<<<1, 64, 0, stream>>>(bct_e, bct_t, meta, blockbase, tblockbase);
    scatter_kernel<<<GB_, 256, 0, stream>>>(top4p, blockbase, task_id, tpp, tblockbase,
                                            pair_sample, pair_dst, torder);
    gemm9<IN_, 1><<<GEMM_GRID, 256, 0, stream>>>(featb, w0T, rb0, sb0, pair_sample, pair_dst, meta, h1);
    gemm4<W_, 2><<<GEMM_GRID, 256, 0, stream>>>(h1, w1T, rb1, sb1, pair_sample, pair_dst, meta, h2);
    combine4<<<CB_GRID, 256, 0, stream>>>(h2, w6, torder, meta, hkb, hb, out);
}